// Round 1
// baseline (1918.018 us; speedup 1.0000x reference)
//
#include <hip/hip_runtime.h>

#define B_ 4
#define S_ 4096
#define D_ 1024
#define E_ 8
#define I_ 2048
#define K_ 1024

typedef __attribute__((ext_vector_type(8))) short short8;
typedef __attribute__((ext_vector_type(4))) float f32x4;

__device__ __forceinline__ short f2bf(float f) {
  union { float f; unsigned u; } v; v.f = f;
  unsigned r = v.u + 0x7FFFu + ((v.u >> 16) & 1u);
  return (short)(r >> 16);
}

// ---------------- Router: logits + softmax in f64, one wave per token ----------------
__global__ __launch_bounds__(256) void router_kernel(const float* __restrict__ x,
                                                     const float* __restrict__ gw,
                                                     double* __restrict__ affD) {
  int wave = threadIdx.x >> 6, lane = threadIdx.x & 63;
  int tok = blockIdx.x * 4 + wave;          // tok = b*S + s
  int b = tok >> 12, s = tok & (S_ - 1);
  const float* xr = x + (size_t)tok * D_;
  double acc[E_];
#pragma unroll
  for (int e = 0; e < E_; ++e) acc[e] = 0.0;
#pragma unroll 4
  for (int r = 0; r < 16; ++r) {
    int d = r * 64 + lane;
    float xv = xr[d];
    const float4* g4 = reinterpret_cast<const float4*>(gw + (size_t)d * E_);
    float4 g0 = g4[0], g1 = g4[1];
    acc[0] += (double)xv * g0.x; acc[1] += (double)xv * g0.y;
    acc[2] += (double)xv * g0.z; acc[3] += (double)xv * g0.w;
    acc[4] += (double)xv * g1.x; acc[5] += (double)xv * g1.y;
    acc[6] += (double)xv * g1.z; acc[7] += (double)xv * g1.w;
  }
#pragma unroll
  for (int off = 32; off > 0; off >>= 1) {
#pragma unroll
    for (int e = 0; e < E_; ++e) acc[e] += __shfl_xor(acc[e], off, 64);
  }
  double m = acc[0];
#pragma unroll
  for (int e = 1; e < E_; ++e) m = acc[e] > m ? acc[e] : m;
  double den = 0.0, ex[E_];
#pragma unroll
  for (int e = 0; e < E_; ++e) { ex[e] = exp(acc[e] - m); den += ex[e]; }
  if (lane < E_)
    affD[((size_t)b * E_ + lane) * S_ + s] = ex[lane] / den;
}

// ---------------- Top-K per (b,e): bitonic sort of 4096 f64-bit keys in LDS ----------------
__global__ __launch_bounds__(1024) void topk_kernel(const double* __restrict__ affD,
                                                    int* __restrict__ idxArr,
                                                    float* __restrict__ gateArr) {
  __shared__ unsigned long long keys[S_];
  __shared__ int sidx[S_];
  int be = blockIdx.x, tid = threadIdx.x;
  const double* a = affD + (size_t)be * S_;
  for (int t = tid; t < S_; t += 1024) {
    keys[t] = (unsigned long long)__double_as_longlong(a[t]); // positive doubles: bit order == value order
    sidx[t] = t;
  }
  __syncthreads();
  for (int k = 2; k <= S_; k <<= 1) {
    for (int j = k >> 1; j > 0; j >>= 1) {
      for (int t = tid; t < S_; t += 1024) {
        int x2 = t ^ j;
        if (x2 > t) {
          unsigned long long ka = keys[t], kb = keys[x2];
          int ia = sidx[t], ib = sidx[x2];
          bool agt = (ka > kb) || (ka == kb && ia < ib);  // tie → lower index "greater" (jax top_k)
          bool up = ((t & k) == 0);
          if (up == agt) {
            keys[t] = kb; keys[x2] = ka;
            sidx[t] = ib; sidx[x2] = ia;
          }
        }
      }
      __syncthreads();
    }
  }
  // ascending sort → top-K at the tail
  for (int t = tid; t < K_; t += 1024) {
    int p = S_ - 1 - t;
    gateArr[(size_t)be * K_ + t] = (float)__longlong_as_double((long long)keys[p]);
    idxArr[(size_t)be * K_ + t] = sidx[p];
  }
}

// ---------------- Stage 1: H = silu(Xsel@Wg) * (Xsel@Wu), bf16 MFMA 128x128 tile ----------------
__global__ __launch_bounds__(256, 2) void mlp1_kernel(
    const float* __restrict__ x, const float* __restrict__ Wg,
    const float* __restrict__ Wu, const int* __restrict__ idxArr,
    unsigned short* __restrict__ H, int Ic, int i0) {
  const int Nt = Ic >> 7;
  int bid = blockIdx.x;
  int nt = bid % Nt; bid /= Nt;
  int mt = bid & 7; bid >>= 3;
  int be = bid;
  int b = be >> 3, e = be & 7;

  __shared__ short lsA[128 * 72];
  __shared__ short lsBg[128 * 72];
  __shared__ short lsBu[128 * 72];
  __shared__ int sTok[128];

  int tid = threadIdx.x;
  if (tid < 128) sTok[tid] = idxArr[(size_t)be * K_ + mt * 128 + tid];
  __syncthreads();

  const float* xb = x + (size_t)b * S_ * D_;
  const float* wg = Wg + (size_t)e * D_ * I_ + i0 + nt * 128;
  const float* wu = Wu + (size_t)e * D_ * I_ + i0 + nt * 128;

  int w = tid >> 6, lane = tid & 63;
  int wm = w >> 1, wn = w & 1;
  int lr = lane & 15, lg = lane >> 4;

  f32x4 accg[4][4], accu[4][4];
#pragma unroll
  for (int i = 0; i < 4; ++i)
#pragma unroll
    for (int j = 0; j < 4; ++j) {
      accg[i][j] = (f32x4){0.f, 0.f, 0.f, 0.f};
      accu[i][j] = (f32x4){0.f, 0.f, 0.f, 0.f};
    }

  int bn = tid & 127, bkh = tid >> 7;

  for (int k0 = 0; k0 < D_; k0 += 64) {
    // stage A: gathered token rows, f32 -> bf16
#pragma unroll
    for (int c = 0; c < 4; ++c) {
      int flat = (c * 256 + tid) * 8;
      int row = flat >> 6, col = flat & 63;
      const float* src = xb + (size_t)sTok[row] * D_ + k0 + col;
      float4 f0 = *reinterpret_cast<const float4*>(src);
      float4 f1 = *reinterpret_cast<const float4*>(src + 4);
      short8 t;
      t[0] = f2bf(f0.x); t[1] = f2bf(f0.y); t[2] = f2bf(f0.z); t[3] = f2bf(f0.w);
      t[4] = f2bf(f1.x); t[5] = f2bf(f1.y); t[6] = f2bf(f1.z); t[7] = f2bf(f1.w);
      *reinterpret_cast<short8*>(&lsA[row * 72 + col]) = t;
    }
    // stage Bg/Bu transposed into [n][k] (k contiguous for b128 frag reads)
    {
      const float* pg = wg + (size_t)(k0 + bkh * 32) * I_ + bn;
      const float* pu = wu + (size_t)(k0 + bkh * 32) * I_ + bn;
#pragma unroll
      for (int w8 = 0; w8 < 4; ++w8) {
        short8 tg, tu;
#pragma unroll
        for (int j = 0; j < 8; ++j) {
          tg[j] = f2bf(pg[(size_t)(w8 * 8 + j) * I_]);
          tu[j] = f2bf(pu[(size_t)(w8 * 8 + j) * I_]);
        }
        *reinterpret_cast<short8*>(&lsBg[bn * 72 + bkh * 32 + w8 * 8]) = tg;
        *reinterpret_cast<short8*>(&lsBu[bn * 72 + bkh * 32 + w8 * 8]) = tu;
      }
    }
    __syncthreads();
#pragma unroll
    for (int fk = 0; fk < 2; ++fk) {
      short8 af[4], bgf[4], buf[4];
#pragma unroll
      for (int fm = 0; fm < 4; ++fm)
        af[fm] = *reinterpret_cast<short8*>(&lsA[(wm * 64 + fm * 16 + lr) * 72 + fk * 32 + lg * 8]);
#pragma unroll
      for (int fn = 0; fn < 4; ++fn) {
        bgf[fn] = *reinterpret_cast<short8*>(&lsBg[(wn * 64 + fn * 16 + lr) * 72 + fk * 32 + lg * 8]);
        buf[fn] = *reinterpret_cast<short8*>(&lsBu[(wn * 64 + fn * 16 + lr) * 72 + fk * 32 + lg * 8]);
      }
#pragma unroll
      for (int fm = 0; fm < 4; ++fm)
#pragma unroll
        for (int fn = 0; fn < 4; ++fn) {
          accg[fm][fn] = __builtin_amdgcn_mfma_f32_16x16x32_bf16(af[fm], bgf[fn], accg[fm][fn], 0, 0, 0);
          accu[fm][fn] = __builtin_amdgcn_mfma_f32_16x16x32_bf16(af[fm], buf[fn], accu[fm][fn], 0, 0, 0);
        }
    }
    __syncthreads();
  }
  // epilogue: h = silu(g)*u -> bf16 H
  unsigned short* Hbe = H + (size_t)be * K_ * Ic;
#pragma unroll
  for (int fm = 0; fm < 4; ++fm)
#pragma unroll
    for (int fn = 0; fn < 4; ++fn) {
#pragma unroll
      for (int j = 0; j < 4; ++j) {
        float g = accg[fm][fn][j], u = accu[fm][fn][j];
        float h = g / (1.f + __expf(-g)) * u;
        int row = wm * 64 + fm * 16 + lg * 4 + j;
        int col = wn * 64 + fn * 16 + lr;
        Hbe[(size_t)(mt * 128 + row) * Ic + nt * 128 + col] = (unsigned short)f2bf(h);
      }
    }
}

// ---------------- Stage 2: Out = H @ Wd, scatter atomicAdd * gating ----------------
__global__ __launch_bounds__(256, 2) void mlp2_kernel(
    const unsigned short* __restrict__ H, const float* __restrict__ Wd,
    const int* __restrict__ idxArr, const float* __restrict__ gateArr,
    float* __restrict__ out, int Ic, int i0) {
  int bid = blockIdx.x;
  int nt = bid & 7; bid >>= 3;
  int mt = bid & 7; bid >>= 3;
  int be = bid;
  int b = be >> 3, e = be & 7;

  __shared__ short lsA[128 * 72];
  __shared__ short lsB[128 * 72];
  __shared__ int sTok[128];
  __shared__ float sGate[128];

  int tid = threadIdx.x;
  if (tid < 128) {
    sTok[tid] = idxArr[(size_t)be * K_ + mt * 128 + tid];
    sGate[tid] = gateArr[(size_t)be * K_ + mt * 128 + tid];
  }
  __syncthreads();

  const short* Hbe = reinterpret_cast<const short*>(H) + (size_t)be * K_ * Ic;
  const float* wd = Wd + (size_t)e * I_ * D_ + (size_t)i0 * D_ + nt * 128;

  int w = tid >> 6, lane = tid & 63;
  int wm = w >> 1, wn = w & 1;
  int lr = lane & 15, lg = lane >> 4;

  f32x4 acc[4][4];
#pragma unroll
  for (int i = 0; i < 4; ++i)
#pragma unroll
    for (int j = 0; j < 4; ++j) acc[i][j] = (f32x4){0.f, 0.f, 0.f, 0.f};

  int bn = tid & 127, bkh = tid >> 7;

  for (int k0 = 0; k0 < Ic; k0 += 64) {
    // stage A: H rows (already bf16, plain copy)
#pragma unroll
    for (int c = 0; c < 4; ++c) {
      int flat = (c * 256 + tid) * 8;
      int row = flat >> 6, col = flat & 63;
      short8 t = *reinterpret_cast<const short8*>(Hbe + (size_t)(mt * 128 + row) * Ic + k0 + col);
      *reinterpret_cast<short8*>(&lsA[row * 72 + col]) = t;
    }
    // stage B: Wd rows, f32 -> bf16, transposed [n][k]
    {
      const float* pd = wd + (size_t)(k0 + bkh * 32) * D_ + bn;
#pragma unroll
      for (int w8 = 0; w8 < 4; ++w8) {
        short8 t;
#pragma unroll
        for (int j = 0; j < 8; ++j) t[j] = f2bf(pd[(size_t)(w8 * 8 + j) * D_]);
        *reinterpret_cast<short8*>(&lsB[bn * 72 + bkh * 32 + w8 * 8]) = t;
      }
    }
    __syncthreads();
#pragma unroll
    for (int fk = 0; fk < 2; ++fk) {
      short8 af[4], bf[4];
#pragma unroll
      for (int fm = 0; fm < 4; ++fm)
        af[fm] = *reinterpret_cast<short8*>(&lsA[(wm * 64 + fm * 16 + lr) * 72 + fk * 32 + lg * 8]);
#pragma unroll
      for (int fn = 0; fn < 4; ++fn)
        bf[fn] = *reinterpret_cast<short8*>(&lsB[(wn * 64 + fn * 16 + lr) * 72 + fk * 32 + lg * 8]);
#pragma unroll
      for (int fm = 0; fm < 4; ++fm)
#pragma unroll
        for (int fn = 0; fn < 4; ++fn)
          acc[fm][fn] = __builtin_amdgcn_mfma_f32_16x16x32_bf16(af[fm], bf[fn], acc[fm][fn], 0, 0, 0);
    }
    __syncthreads();
  }
  // epilogue: weighted scatter-add
#pragma unroll
  for (int fm = 0; fm < 4; ++fm)
#pragma unroll
    for (int fn = 0; fn < 4; ++fn) {
#pragma unroll
      for (int j = 0; j < 4; ++j) {
        int row = wm * 64 + fm * 16 + lg * 4 + j;
        int col = nt * 128 + wn * 64 + fn * 16 + lr;
        float v = acc[fm][fn][j] * sGate[row];
        atomicAdd(&out[((size_t)b * S_ + sTok[row]) * D_ + col], v);
      }
    }
}

extern "C" void kernel_launch(void* const* d_in, const int* in_sizes, int n_in,
                              void* d_out, int out_size, void* d_ws, size_t ws_size,
                              hipStream_t stream) {
  const float* x  = (const float*)d_in[0];
  const float* gw = (const float*)d_in[1];
  const float* Wg = (const float*)d_in[2];
  const float* Wu = (const float*)d_in[3];
  const float* Wd = (const float*)d_in[4];
  float* out = (float*)d_out;
  char* ws = (char*)d_ws;

  size_t off = 0;
  double* affD = (double*)(ws + off); off += (size_t)B_ * E_ * S_ * sizeof(double);  // 1 MB
  int* idxArr = (int*)(ws + off);     off += (size_t)B_ * E_ * K_ * sizeof(int);     // 128 KB
  float* gateArr = (float*)(ws + off); off += (size_t)B_ * E_ * K_ * sizeof(float);  // 128 KB
  off = (off + 255) & ~(size_t)255;
  unsigned short* H = (unsigned short*)(ws + off);
  size_t rem = (ws_size > off) ? (ws_size - off) : 0;

  int Ic = 128;  // I-chunk for H buffer, sized to workspace
  for (int c = I_; c >= 128; c >>= 1) {
    if ((size_t)B_ * E_ * K_ * (size_t)c * 2 <= rem) { Ic = c; break; }
  }

  hipMemsetAsync(d_out, 0, (size_t)out_size * sizeof(float), stream);
  router_kernel<<<B_ * S_ / 4, 256, 0, stream>>>(x, gw, affD);
  topk_kernel<<<B_ * E_, 1024, 0, stream>>>(affD, idxArr, gateArr);
  for (int i0 = 0; i0 < I_; i0 += Ic) {
    mlp1_kernel<<<B_ * E_ * 8 * (Ic / 128), 256, 0, stream>>>(x, Wg, Wu, idxArr, H, Ic, i0);
    mlp2_kernel<<<B_ * E_ * 8 * 8, 256, 0, stream>>>(H, Wd, idxArr, gateArr, out, Ic, i0);
  }
}

// Round 2
// 805.381 us; speedup vs baseline: 2.3815x; 2.3815x over previous
//
#include <hip/hip_runtime.h>

#define B_ 4
#define S_ 4096
#define D_ 1024
#define E_ 8
#define I_ 2048
#define K_ 1024

typedef __attribute__((ext_vector_type(8))) short short8;
typedef __attribute__((ext_vector_type(4))) float f32x4;

__device__ __forceinline__ short f2bf(float f) {
  union { float f; unsigned u; } v; v.f = f;
  unsigned r = v.u + 0x7FFFu + ((v.u >> 16) & 1u);
  return (short)(r >> 16);
}

__device__ __forceinline__ void gload16(const void* g, void* l) {
  __builtin_amdgcn_global_load_lds((const __attribute__((address_space(1))) unsigned int*)g,
                                   (__attribute__((address_space(3))) unsigned int*)l, 16, 0, 0);
}

// ---------------- Router: logits + softmax in f64, one wave per token ----------------
__global__ __launch_bounds__(256) void router_kernel(const float* __restrict__ x,
                                                     const float* __restrict__ gw,
                                                     double* __restrict__ affD) {
  int wave = threadIdx.x >> 6, lane = threadIdx.x & 63;
  int tok = blockIdx.x * 4 + wave;          // tok = b*S + s
  int b = tok >> 12, s = tok & (S_ - 1);
  const float* xr = x + (size_t)tok * D_;
  double acc[E_];
#pragma unroll
  for (int e = 0; e < E_; ++e) acc[e] = 0.0;
#pragma unroll 4
  for (int r = 0; r < 16; ++r) {
    int d = r * 64 + lane;
    float xv = xr[d];
    const float4* g4 = reinterpret_cast<const float4*>(gw + (size_t)d * E_);
    float4 g0 = g4[0], g1 = g4[1];
    acc[0] += (double)xv * g0.x; acc[1] += (double)xv * g0.y;
    acc[2] += (double)xv * g0.z; acc[3] += (double)xv * g0.w;
    acc[4] += (double)xv * g1.x; acc[5] += (double)xv * g1.y;
    acc[6] += (double)xv * g1.z; acc[7] += (double)xv * g1.w;
  }
#pragma unroll
  for (int off = 32; off > 0; off >>= 1) {
#pragma unroll
    for (int e = 0; e < E_; ++e) acc[e] += __shfl_xor(acc[e], off, 64);
  }
  double m = acc[0];
#pragma unroll
  for (int e = 1; e < E_; ++e) m = acc[e] > m ? acc[e] : m;
  double den = 0.0, ex[E_];
#pragma unroll
  for (int e = 0; e < E_; ++e) { ex[e] = exp(acc[e] - m); den += ex[e]; }
  if (lane < E_)
    affD[((size_t)b * E_ + lane) * S_ + s] = ex[lane] / den;
}

// ---------------- Top-K per (b,e): bitonic sort of 4096 f64-bit keys in LDS ----------------
__global__ __launch_bounds__(1024) void topk_kernel(const double* __restrict__ affD,
                                                    int* __restrict__ idxArr,
                                                    float* __restrict__ gateArr) {
  __shared__ unsigned long long keys[S_];
  __shared__ int sidx[S_];
  int be = blockIdx.x, tid = threadIdx.x;
  const double* a = affD + (size_t)be * S_;
  for (int t = tid; t < S_; t += 1024) {
    keys[t] = (unsigned long long)__double_as_longlong(a[t]); // positive doubles: bit order == value order
    sidx[t] = t;
  }
  __syncthreads();
  for (int k = 2; k <= S_; k <<= 1) {
    for (int j = k >> 1; j > 0; j >>= 1) {
      for (int t = tid; t < S_; t += 1024) {
        int x2 = t ^ j;
        if (x2 > t) {
          unsigned long long ka = keys[t], kb = keys[x2];
          int ia = sidx[t], ib = sidx[x2];
          bool agt = (ka > kb) || (ka == kb && ia < ib);  // tie -> lower index "greater" (jax top_k)
          bool up = ((t & k) == 0);
          if (up == agt) {
            keys[t] = kb; keys[x2] = ka;
            sidx[t] = ib; sidx[x2] = ia;
          }
        }
      }
      __syncthreads();
    }
  }
  // ascending sort -> top-K at the tail
  for (int t = tid; t < K_; t += 1024) {
    int p = S_ - 1 - t;
    gateArr[(size_t)be * K_ + t] = (float)__longlong_as_double((long long)keys[p]);
    idxArr[(size_t)be * K_ + t] = sidx[p];
  }
}

// ---------------- Weight transpose + f32->bf16: in f32 [M][N] -> out bf16 [N][M] ----------------
__global__ __launch_bounds__(256) void transpose_cvt_kernel(const float* __restrict__ in,
                                                            unsigned short* __restrict__ out,
                                                            int M, int N) {
  __shared__ float t[64][65];
  int e = blockIdx.y;
  int ntn = N >> 6;
  int tm = (blockIdx.x / ntn) << 6;
  int tn = (blockIdx.x % ntn) << 6;
  const float* src = in + (size_t)e * M * N;
  unsigned short* dst = out + (size_t)e * M * N;
  int tid = threadIdx.x;
#pragma unroll
  for (int it = 0; it < 4; ++it) {
    int f = it * 256 + tid;
    int r = f >> 4, c4 = (f & 15) << 2;
    float4 v = *reinterpret_cast<const float4*>(&src[(size_t)(tm + r) * N + tn + c4]);
    t[c4][r] = v.x; t[c4 + 1][r] = v.y; t[c4 + 2][r] = v.z; t[c4 + 3][r] = v.w;
  }
  __syncthreads();
#pragma unroll
  for (int it = 0; it < 4; ++it) {
    int f = it * 256 + tid;
    int rr = f >> 4, c4 = (f & 15) << 2;
    short4 o;
    o.x = f2bf(t[rr][c4]); o.y = f2bf(t[rr][c4 + 1]);
    o.z = f2bf(t[rr][c4 + 2]); o.w = f2bf(t[rr][c4 + 3]);
    *reinterpret_cast<short4*>(&dst[(size_t)(tn + rr) * M + tm + c4]) = o;
  }
}

// ---------------- Stage 1: H = silu(Xsel@Wg) * (Xsel@Wu), bf16 MFMA 128x128 tile ----------------
__global__ __launch_bounds__(256, 2) void mlp1_kernel(
    const float* __restrict__ x, const unsigned short* __restrict__ WgT,
    const unsigned short* __restrict__ WuT, const int* __restrict__ idxArr,
    unsigned short* __restrict__ H, int Ic, int i0) {
  const int Nt = Ic >> 7;
  int bid = blockIdx.x;
  int nt = bid % Nt; bid /= Nt;
  int mt = bid & 7; bid >>= 3;
  int be = bid;
  int b = be >> 3, e = be & 7;

  __shared__ short lsA[128 * 72];    // padded (reg-staged, conflict-lite)
  __shared__ short lsBg[128 * 64];   // linear (global_load_lds)
  __shared__ short lsBu[128 * 64];
  __shared__ int sTok[128];

  int tid = threadIdx.x;
  if (tid < 128) sTok[tid] = idxArr[(size_t)be * K_ + mt * 128 + tid];
  __syncthreads();

  const float* xb = x + (size_t)b * S_ * D_;
  const char* wg2 = (const char*)(WgT + (size_t)e * I_ * D_ + (size_t)(i0 + nt * 128) * D_);
  const char* wu2 = (const char*)(WuT + (size_t)e * I_ * D_ + (size_t)(i0 + nt * 128) * D_);

  int w = tid >> 6, lane = tid & 63;
  int wm = w >> 1, wn = w & 1;
  int lr = lane & 15, lg = lane >> 4;

  f32x4 accg[4][4], accu[4][4];
#pragma unroll
  for (int i = 0; i < 4; ++i)
#pragma unroll
    for (int j = 0; j < 4; ++j) {
      accg[i][j] = (f32x4){0.f, 0.f, 0.f, 0.f};
      accu[i][j] = (f32x4){0.f, 0.f, 0.f, 0.f};
    }

  for (int k0 = 0; k0 < D_; k0 += 64) {
    // stage A: gathered token rows, f32 -> bf16 (reg-staged)
#pragma unroll
    for (int c = 0; c < 4; ++c) {
      int flat = (c * 256 + tid) * 8;
      int row = flat >> 6, col = flat & 63;
      const float* src = xb + (size_t)sTok[row] * D_ + k0 + col;
      float4 f0 = *reinterpret_cast<const float4*>(src);
      float4 f1 = *reinterpret_cast<const float4*>(src + 4);
      short8 t;
      t[0] = f2bf(f0.x); t[1] = f2bf(f0.y); t[2] = f2bf(f0.z); t[3] = f2bf(f0.w);
      t[4] = f2bf(f1.x); t[5] = f2bf(f1.y); t[6] = f2bf(f1.z); t[7] = f2bf(f1.w);
      *reinterpret_cast<short8*>(&lsA[row * 72 + col]) = t;
    }
    // stage Bg/Bu: bf16 [n][k] tiles straight from HBM via global_load_lds x16B
#pragma unroll
    for (int c = 0; c < 4; ++c) {
      int chunk = c * 4 + w;                 // wave-uniform
      int fb = (chunk * 64 + lane) * 16;     // this lane's byte in the 16KB tile
      int row = fb >> 7, colb = fb & 127;
      size_t goff = (size_t)row * (D_ * 2) + (size_t)k0 * 2 + colb;
      gload16(wg2 + goff, (char*)lsBg + chunk * 1024);
      gload16(wu2 + goff, (char*)lsBu + chunk * 1024);
    }
    __syncthreads();
#pragma unroll
    for (int fk = 0; fk < 2; ++fk) {
      short8 af[4], bgf[4], buf[4];
#pragma unroll
      for (int fm = 0; fm < 4; ++fm)
        af[fm] = *reinterpret_cast<short8*>(&lsA[(wm * 64 + fm * 16 + lr) * 72 + fk * 32 + lg * 8]);
#pragma unroll
      for (int fn = 0; fn < 4; ++fn) {
        bgf[fn] = *reinterpret_cast<short8*>(&lsBg[(wn * 64 + fn * 16 + lr) * 64 + fk * 32 + lg * 8]);
        buf[fn] = *reinterpret_cast<short8*>(&lsBu[(wn * 64 + fn * 16 + lr) * 64 + fk * 32 + lg * 8]);
      }
#pragma unroll
      for (int fm = 0; fm < 4; ++fm)
#pragma unroll
        for (int fn = 0; fn < 4; ++fn) {
          accg[fm][fn] = __builtin_amdgcn_mfma_f32_16x16x32_bf16(af[fm], bgf[fn], accg[fm][fn], 0, 0, 0);
          accu[fm][fn] = __builtin_amdgcn_mfma_f32_16x16x32_bf16(af[fm], buf[fn], accu[fm][fn], 0, 0, 0);
        }
    }
    __syncthreads();
  }
  // epilogue: h = silu(g)*u -> bf16 H
  unsigned short* Hbe = H + (size_t)be * K_ * Ic;
#pragma unroll
  for (int fm = 0; fm < 4; ++fm)
#pragma unroll
    for (int fn = 0; fn < 4; ++fn) {
#pragma unroll
      for (int j = 0; j < 4; ++j) {
        float g = accg[fm][fn][j], u = accu[fm][fn][j];
        float h = g / (1.f + __expf(-g)) * u;
        int row = wm * 64 + fm * 16 + lg * 4 + j;
        int col = wn * 64 + fn * 16 + lr;
        Hbe[(size_t)(mt * 128 + row) * Ic + nt * 128 + col] = (unsigned short)f2bf(h);
      }
    }
}

// ---------------- Stage 2: Out = H @ Wd, scatter atomicAdd * gating ----------------
__global__ __launch_bounds__(256, 2) void mlp2_kernel(
    const unsigned short* __restrict__ H, const unsigned short* __restrict__ WdT,
    const int* __restrict__ idxArr, const float* __restrict__ gateArr,
    float* __restrict__ out, int Ic, int i0) {
  int bid = blockIdx.x;
  int nt = bid & 7; bid >>= 3;
  int mt = bid & 7; bid >>= 3;
  int be = bid;
  int b = be >> 3, e = be & 7;

  __shared__ short lsA[128 * 64];   // linear (global_load_lds)
  __shared__ short lsB[128 * 64];   // linear (global_load_lds)
  __shared__ int sTok[128];
  __shared__ float sGate[128];

  int tid = threadIdx.x;
  if (tid < 128) {
    sTok[tid] = idxArr[(size_t)be * K_ + mt * 128 + tid];
    sGate[tid] = gateArr[(size_t)be * K_ + mt * 128 + tid];
  }
  __syncthreads();

  const char* Hbe = (const char*)(H + (size_t)be * K_ * Ic);
  const char* wd2 = (const char*)(WdT + (size_t)e * D_ * I_);

  int w = tid >> 6, lane = tid & 63;
  int wm = w >> 1, wn = w & 1;
  int lr = lane & 15, lg = lane >> 4;

  f32x4 acc[4][4];
#pragma unroll
  for (int i = 0; i < 4; ++i)
#pragma unroll
    for (int j = 0; j < 4; ++j) acc[i][j] = (f32x4){0.f, 0.f, 0.f, 0.f};

  for (int k0 = 0; k0 < Ic; k0 += 64) {
#pragma unroll
    for (int c = 0; c < 4; ++c) {
      int chunk = c * 4 + w;
      int fb = (chunk * 64 + lane) * 16;
      int row = fb >> 7, colb = fb & 127;
      // A: H rows (tokens), k = I-chunk
      gload16(Hbe + (size_t)(mt * 128 + row) * Ic * 2 + (size_t)k0 * 2 + colb,
              (char*)lsA + chunk * 1024);
      // B: WdT rows (d), k = I
      gload16(wd2 + ((size_t)(nt * 128 + row) * I_ + i0 + k0) * 2 + colb,
              (char*)lsB + chunk * 1024);
    }
    __syncthreads();
#pragma unroll
    for (int fk = 0; fk < 2; ++fk) {
      short8 af[4], bf[4];
#pragma unroll
      for (int fm = 0; fm < 4; ++fm)
        af[fm] = *reinterpret_cast<short8*>(&lsA[(wm * 64 + fm * 16 + lr) * 64 + fk * 32 + lg * 8]);
#pragma unroll
      for (int fn = 0; fn < 4; ++fn)
        bf[fn] = *reinterpret_cast<short8*>(&lsB[(wn * 64 + fn * 16 + lr) * 64 + fk * 32 + lg * 8]);
#pragma unroll
      for (int fm = 0; fm < 4; ++fm)
#pragma unroll
        for (int fn = 0; fn < 4; ++fn)
          acc[fm][fn] = __builtin_amdgcn_mfma_f32_16x16x32_bf16(af[fm], bf[fn], acc[fm][fn], 0, 0, 0);
    }
    __syncthreads();
  }
  // epilogue: weighted scatter-add
#pragma unroll
  for (int fm = 0; fm < 4; ++fm)
#pragma unroll
    for (int fn = 0; fn < 4; ++fn) {
#pragma unroll
      for (int j = 0; j < 4; ++j) {
        int row = wm * 64 + fm * 16 + lg * 4 + j;
        int col = nt * 128 + wn * 64 + fn * 16 + lr;
        float v = acc[fm][fn][j] * sGate[row];
        atomicAdd(&out[((size_t)b * S_ + sTok[row]) * D_ + col], v);
      }
    }
}

extern "C" void kernel_launch(void* const* d_in, const int* in_sizes, int n_in,
                              void* d_out, int out_size, void* d_ws, size_t ws_size,
                              hipStream_t stream) {
  const float* x  = (const float*)d_in[0];
  const float* gw = (const float*)d_in[1];
  const float* Wg = (const float*)d_in[2];
  const float* Wu = (const float*)d_in[3];
  const float* Wd = (const float*)d_in[4];
  float* out = (float*)d_out;
  char* ws = (char*)d_ws;

  size_t off = 0;
  double* affD = (double*)(ws + off); off += (size_t)B_ * E_ * S_ * sizeof(double);  // 1 MB
  int* idxArr = (int*)(ws + off);     off += (size_t)B_ * E_ * K_ * sizeof(int);     // 128 KB
  float* gateArr = (float*)(ws + off); off += (size_t)B_ * E_ * K_ * sizeof(float);  // 128 KB
  off = (off + 255) & ~(size_t)255;
  unsigned short* WgT = (unsigned short*)(ws + off); off += (size_t)E_ * D_ * I_ * 2; // 32 MB
  unsigned short* WuT = (unsigned short*)(ws + off); off += (size_t)E_ * D_ * I_ * 2; // 32 MB
  unsigned short* WdT = (unsigned short*)(ws + off); off += (size_t)E_ * D_ * I_ * 2; // 32 MB
  off = (off + 255) & ~(size_t)255;
  unsigned short* H = (unsigned short*)(ws + off);
  size_t rem = (ws_size > off) ? (ws_size - off) : 0;

  int Ic = 128;  // I-chunk for H buffer, sized to workspace
  for (int c = I_; c >= 128; c >>= 1) {
    if ((size_t)B_ * E_ * K_ * (size_t)c * 2 <= rem) { Ic = c; break; }
  }

  hipMemsetAsync(d_out, 0, (size_t)out_size * sizeof(float), stream);
  router_kernel<<<B_ * S_ / 4, 256, 0, stream>>>(x, gw, affD);
  topk_kernel<<<B_ * E_, 1024, 0, stream>>>(affD, idxArr, gateArr);
  // weight pre-transpose+convert: Wg,Wu [D][I] -> [I][D]; Wd [I][D] -> [D][I]
  transpose_cvt_kernel<<<dim3((D_ / 64) * (I_ / 64), E_), 256, 0, stream>>>(Wg, WgT, D_, I_);
  transpose_cvt_kernel<<<dim3((D_ / 64) * (I_ / 64), E_), 256, 0, stream>>>(Wu, WuT, D_, I_);
  transpose_cvt_kernel<<<dim3((I_ / 64) * (D_ / 64), E_), 256, 0, stream>>>(Wd, WdT, I_, D_);
  for (int i0 = 0; i0 < I_; i0 += Ic) {
    mlp1_kernel<<<B_ * E_ * 8 * (Ic / 128), 256, 0, stream>>>(x, WgT, WuT, idxArr, H, Ic, i0);
    mlp2_kernel<<<B_ * E_ * 8 * 8, 256, 0, stream>>>(H, WdT, idxArr, gateArr, out, Ic, i0);
  }
}

// Round 3
// 801.192 us; speedup vs baseline: 2.3940x; 1.0052x over previous
//
#include <hip/hip_runtime.h>

#define B_ 4
#define S_ 4096
#define D_ 1024
#define E_ 8
#define I_ 2048
#define K_ 1024

typedef __attribute__((ext_vector_type(8))) short short8;
typedef __attribute__((ext_vector_type(4))) float f32x4;

__device__ __forceinline__ short f2bf(float f) {
  union { float f; unsigned u; } v; v.f = f;
  unsigned r = v.u + 0x7FFFu + ((v.u >> 16) & 1u);
  return (short)(r >> 16);
}

__device__ __forceinline__ void gload16(const void* g, void* l) {
  __builtin_amdgcn_global_load_lds((const __attribute__((address_space(1))) unsigned int*)g,
                                   (__attribute__((address_space(3))) unsigned int*)l, 16, 0, 0);
}

// swizzled LDS fragment read: tile is [128 rows][128 bytes], byte col XORed by ((row&7)<<4)
__device__ __forceinline__ short8 rdswz(const short* ls, int row, int cb) {
  int byte = (row << 7) + (cb ^ ((row & 7) << 4));
  return *reinterpret_cast<const short8*>(reinterpret_cast<const char*>(ls) + byte);
}

// ---------------- Router: logits + softmax in f64, one wave per token ----------------
__global__ __launch_bounds__(256) void router_kernel(const float* __restrict__ x,
                                                     const float* __restrict__ gw,
                                                     double* __restrict__ affD) {
  int wave = threadIdx.x >> 6, lane = threadIdx.x & 63;
  int tok = blockIdx.x * 4 + wave;          // tok = b*S + s
  int b = tok >> 12, s = tok & (S_ - 1);
  const float* xr = x + (size_t)tok * D_;
  double acc[E_];
#pragma unroll
  for (int e = 0; e < E_; ++e) acc[e] = 0.0;
#pragma unroll 4
  for (int r = 0; r < 16; ++r) {
    int d = r * 64 + lane;
    float xv = xr[d];
    const float4* g4 = reinterpret_cast<const float4*>(gw + (size_t)d * E_);
    float4 g0 = g4[0], g1 = g4[1];
    acc[0] += (double)xv * g0.x; acc[1] += (double)xv * g0.y;
    acc[2] += (double)xv * g0.z; acc[3] += (double)xv * g0.w;
    acc[4] += (double)xv * g1.x; acc[5] += (double)xv * g1.y;
    acc[6] += (double)xv * g1.z; acc[7] += (double)xv * g1.w;
  }
#pragma unroll
  for (int off = 32; off > 0; off >>= 1) {
#pragma unroll
    for (int e = 0; e < E_; ++e) acc[e] += __shfl_xor(acc[e], off, 64);
  }
  double m = acc[0];
#pragma unroll
  for (int e = 1; e < E_; ++e) m = acc[e] > m ? acc[e] : m;
  double den = 0.0, ex[E_];
#pragma unroll
  for (int e = 0; e < E_; ++e) { ex[e] = exp(acc[e] - m); den += ex[e]; }
  if (lane < E_)
    affD[((size_t)b * E_ + lane) * S_ + s] = ex[lane] / den;
}

// ---------------- Top-K per (b,e): bitonic sort of 4096 f64-bit keys in LDS ----------------
__global__ __launch_bounds__(1024) void topk_kernel(const double* __restrict__ affD,
                                                    int* __restrict__ idxArr,
                                                    float* __restrict__ gateArr) {
  __shared__ unsigned long long keys[S_];
  __shared__ int sidx[S_];
  int be = blockIdx.x, tid = threadIdx.x;
  const double* a = affD + (size_t)be * S_;
  for (int t = tid; t < S_; t += 1024) {
    keys[t] = (unsigned long long)__double_as_longlong(a[t]); // positive doubles: bit order == value order
    sidx[t] = t;
  }
  __syncthreads();
  for (int k = 2; k <= S_; k <<= 1) {
    for (int j = k >> 1; j > 0; j >>= 1) {
      for (int t = tid; t < S_; t += 1024) {
        int x2 = t ^ j;
        if (x2 > t) {
          unsigned long long ka = keys[t], kb = keys[x2];
          int ia = sidx[t], ib = sidx[x2];
          bool agt = (ka > kb) || (ka == kb && ia < ib);  // tie -> lower index "greater" (jax top_k)
          bool up = ((t & k) == 0);
          if (up == agt) {
            keys[t] = kb; keys[x2] = ka;
            sidx[t] = ib; sidx[x2] = ia;
          }
        }
      }
      __syncthreads();
    }
  }
  // ascending sort -> top-K at the tail
  for (int t = tid; t < K_; t += 1024) {
    int p = S_ - 1 - t;
    gateArr[(size_t)be * K_ + t] = (float)__longlong_as_double((long long)keys[p]);
    idxArr[(size_t)be * K_ + t] = sidx[p];
  }
}

// ---------------- Weight transpose + f32->bf16: in f32 [M][N] -> out bf16 [N][M] ----------------
__global__ __launch_bounds__(256) void transpose_cvt_kernel(const float* __restrict__ in,
                                                            unsigned short* __restrict__ out,
                                                            int M, int N) {
  __shared__ float t[64][65];
  int e = blockIdx.y;
  int ntn = N >> 6;
  int tm = (blockIdx.x / ntn) << 6;
  int tn = (blockIdx.x % ntn) << 6;
  const float* src = in + (size_t)e * M * N;
  unsigned short* dst = out + (size_t)e * M * N;
  int tid = threadIdx.x;
#pragma unroll
  for (int it = 0; it < 4; ++it) {
    int f = it * 256 + tid;
    int r = f >> 4, c4 = (f & 15) << 2;
    float4 v = *reinterpret_cast<const float4*>(&src[(size_t)(tm + r) * N + tn + c4]);
    t[c4][r] = v.x; t[c4 + 1][r] = v.y; t[c4 + 2][r] = v.z; t[c4 + 3][r] = v.w;
  }
  __syncthreads();
#pragma unroll
  for (int it = 0; it < 4; ++it) {
    int f = it * 256 + tid;
    int rr = f >> 4, c4 = (f & 15) << 2;
    short4 o;
    o.x = f2bf(t[rr][c4]); o.y = f2bf(t[rr][c4 + 1]);
    o.z = f2bf(t[rr][c4 + 2]); o.w = f2bf(t[rr][c4 + 3]);
    *reinterpret_cast<short4*>(&dst[(size_t)(tn + rr) * M + tm + c4]) = o;
  }
}

// ---------------- Gather selected tokens + cvt to bf16: Xsel[be][k][d] ----------------
__global__ __launch_bounds__(256) void gather_cvt_kernel(const float* __restrict__ x,
                                                         const int* __restrict__ idxArr,
                                                         unsigned short* __restrict__ Xsel) {
  int row = blockIdx.x * 4 + (threadIdx.x >> 6);  // be*K_ + k
  int lane = threadIdx.x & 63;
  int b = row >> 13;                              // be>>3
  int tok = idxArr[row];
  const float* src = x + ((size_t)b * S_ + tok) * D_;
  unsigned short* dst = Xsel + (size_t)row * D_;
#pragma unroll
  for (int it = 0; it < 4; ++it) {
    int d = it * 256 + lane * 4;
    float4 v = *reinterpret_cast<const float4*>(src + d);
    short4 o;
    o.x = f2bf(v.x); o.y = f2bf(v.y); o.z = f2bf(v.z); o.w = f2bf(v.w);
    *reinterpret_cast<short4*>(dst + d) = o;
  }
}

// ---------------- Stage 1: H = silu(Xsel@WgT^T) * (Xsel@WuT^T), all-DMA staging ----------------
__global__ __launch_bounds__(256, 2) void mlp1_kernel(
    const unsigned short* __restrict__ Xsel, const unsigned short* __restrict__ WgT,
    const unsigned short* __restrict__ WuT, unsigned short* __restrict__ H,
    int Ic, int i0) {
  const int Nt = Ic >> 7;
  int nwg = gridDim.x;
  int bid = (blockIdx.x & 7) * (nwg >> 3) + (blockIdx.x >> 3);  // XCD swizzle (nwg%8==0)
  int nt = bid % Nt; bid /= Nt;
  int mt = bid & 7; bid >>= 3;
  int be = bid;
  int e = be & 7;

  __shared__ short lsA[128 * 64];
  __shared__ short lsBg[128 * 64];
  __shared__ short lsBu[128 * 64];

  int tid = threadIdx.x, w = tid >> 6, lane = tid & 63;
  int wm = w >> 1, wn = w & 1;
  int lr = lane & 15, lg = lane >> 4;

  const char* pa = (const char*)(Xsel + ((size_t)be * K_ + mt * 128) * D_);
  const char* pg = (const char*)(WgT + (size_t)e * I_ * D_ + (size_t)(i0 + nt * 128) * D_);
  const char* pu = (const char*)(WuT + (size_t)e * I_ * D_ + (size_t)(i0 + nt * 128) * D_);

  int srow = lane >> 3;                      // row within 8-row chunk
  int scol = ((lane & 7) ^ srow) << 4;       // pre-swizzled source byte col

  f32x4 accg[4][4], accu[4][4];
#pragma unroll
  for (int i = 0; i < 4; ++i)
#pragma unroll
    for (int j = 0; j < 4; ++j) {
      accg[i][j] = (f32x4){0.f, 0.f, 0.f, 0.f};
      accu[i][j] = (f32x4){0.f, 0.f, 0.f, 0.f};
    }

  for (int k0 = 0; k0 < D_; k0 += 64) {
#pragma unroll
    for (int c = 0; c < 4; ++c) {
      int chunk = c * 4 + w;                 // wave-uniform
      int row = chunk * 8 + srow;
      size_t go = (size_t)row * (D_ * 2) + (size_t)k0 * 2 + scol;
      gload16(pa + go, (char*)lsA + chunk * 1024);
      gload16(pg + go, (char*)lsBg + chunk * 1024);
      gload16(pu + go, (char*)lsBu + chunk * 1024);
    }
    __syncthreads();
#pragma unroll
    for (int fk = 0; fk < 2; ++fk) {
      int cb = fk * 64 + lg * 16;
      short8 af[4], bgf[4], buf[4];
#pragma unroll
      for (int fm = 0; fm < 4; ++fm)
        af[fm] = rdswz(lsA, wm * 64 + fm * 16 + lr, cb);
#pragma unroll
      for (int fn = 0; fn < 4; ++fn) {
        bgf[fn] = rdswz(lsBg, wn * 64 + fn * 16 + lr, cb);
        buf[fn] = rdswz(lsBu, wn * 64 + fn * 16 + lr, cb);
      }
#pragma unroll
      for (int fm = 0; fm < 4; ++fm)
#pragma unroll
        for (int fn = 0; fn < 4; ++fn) {
          accg[fm][fn] = __builtin_amdgcn_mfma_f32_16x16x32_bf16(af[fm], bgf[fn], accg[fm][fn], 0, 0, 0);
          accu[fm][fn] = __builtin_amdgcn_mfma_f32_16x16x32_bf16(af[fm], buf[fn], accu[fm][fn], 0, 0, 0);
        }
    }
    __syncthreads();
  }
  // epilogue: h = silu(g)*u -> bf16 H
  unsigned short* Hbe = H + (size_t)be * K_ * Ic;
#pragma unroll
  for (int fm = 0; fm < 4; ++fm)
#pragma unroll
    for (int fn = 0; fn < 4; ++fn) {
#pragma unroll
      for (int j = 0; j < 4; ++j) {
        float g = accg[fm][fn][j], u = accu[fm][fn][j];
        float h = g / (1.f + __expf(-g)) * u;
        int row = wm * 64 + fm * 16 + lg * 4 + j;
        int col = wn * 64 + fn * 16 + lr;
        Hbe[(size_t)(mt * 128 + row) * Ic + nt * 128 + col] = (unsigned short)f2bf(h);
      }
    }
}

// ---------------- Stage 2: Out = H @ WdT^T, scatter atomicAdd * gating ----------------
__global__ __launch_bounds__(256, 2) void mlp2_kernel(
    const unsigned short* __restrict__ H, const unsigned short* __restrict__ WdT,
    const int* __restrict__ idxArr, const float* __restrict__ gateArr,
    float* __restrict__ out, int Ic, int i0) {
  int nwg = gridDim.x;
  int bid = (blockIdx.x & 7) * (nwg >> 3) + (blockIdx.x >> 3);  // XCD swizzle
  int nt = bid & 7; bid >>= 3;
  int mt = bid & 7; bid >>= 3;
  int be = bid;
  int b = be >> 3, e = be & 7;

  __shared__ short lsA[128 * 64];
  __shared__ short lsB[128 * 64];
  __shared__ int sTok[128];
  __shared__ float sGate[128];

  int tid = threadIdx.x;
  if (tid < 128) {
    sTok[tid] = idxArr[(size_t)be * K_ + mt * 128 + tid];
    sGate[tid] = gateArr[(size_t)be * K_ + mt * 128 + tid];
  }

  const char* pa = (const char*)(H + ((size_t)be * K_ + mt * 128) * Ic);
  const char* pb = (const char*)(WdT + (size_t)e * D_ * I_ + (size_t)(nt * 128) * I_ + i0);

  int w = tid >> 6, lane = tid & 63;
  int wm = w >> 1, wn = w & 1;
  int lr = lane & 15, lg = lane >> 4;

  int srow = lane >> 3;
  int scol = ((lane & 7) ^ srow) << 4;

  f32x4 acc[4][4];
#pragma unroll
  for (int i = 0; i < 4; ++i)
#pragma unroll
    for (int j = 0; j < 4; ++j) acc[i][j] = (f32x4){0.f, 0.f, 0.f, 0.f};

  for (int k0 = 0; k0 < Ic; k0 += 64) {
#pragma unroll
    for (int c = 0; c < 4; ++c) {
      int chunk = c * 4 + w;
      int row = chunk * 8 + srow;
      gload16(pa + (size_t)row * (Ic * 2) + (size_t)k0 * 2 + scol, (char*)lsA + chunk * 1024);
      gload16(pb + (size_t)row * (I_ * 2) + (size_t)k0 * 2 + scol, (char*)lsB + chunk * 1024);
    }
    __syncthreads();
#pragma unroll
    for (int fk = 0; fk < 2; ++fk) {
      int cb = fk * 64 + lg * 16;
      short8 af[4], bf[4];
#pragma unroll
      for (int fm = 0; fm < 4; ++fm)
        af[fm] = rdswz(lsA, wm * 64 + fm * 16 + lr, cb);
#pragma unroll
      for (int fn = 0; fn < 4; ++fn)
        bf[fn] = rdswz(lsB, wn * 64 + fn * 16 + lr, cb);
#pragma unroll
      for (int fm = 0; fm < 4; ++fm)
#pragma unroll
        for (int fn = 0; fn < 4; ++fn)
          acc[fm][fn] = __builtin_amdgcn_mfma_f32_16x16x32_bf16(af[fm], bf[fn], acc[fm][fn], 0, 0, 0);
    }
    __syncthreads();
  }
  // epilogue: weighted scatter-add
#pragma unroll
  for (int fm = 0; fm < 4; ++fm)
#pragma unroll
    for (int fn = 0; fn < 4; ++fn) {
#pragma unroll
      for (int j = 0; j < 4; ++j) {
        int row = wm * 64 + fm * 16 + lg * 4 + j;
        int col = nt * 128 + wn * 64 + fn * 16 + lr;
        float v = acc[fm][fn][j] * sGate[row];
        atomicAdd(&out[((size_t)b * S_ + sTok[row]) * D_ + col], v);
      }
    }
}

extern "C" void kernel_launch(void* const* d_in, const int* in_sizes, int n_in,
                              void* d_out, int out_size, void* d_ws, size_t ws_size,
                              hipStream_t stream) {
  const float* x  = (const float*)d_in[0];
  const float* gw = (const float*)d_in[1];
  const float* Wg = (const float*)d_in[2];
  const float* Wu = (const float*)d_in[3];
  const float* Wd = (const float*)d_in[4];
  float* out = (float*)d_out;
  char* ws = (char*)d_ws;

  size_t off = 0;
  double* affD = (double*)(ws + off); off += (size_t)B_ * E_ * S_ * sizeof(double);  // 1 MB
  int* idxArr = (int*)(ws + off);     off += (size_t)B_ * E_ * K_ * sizeof(int);     // 128 KB
  float* gateArr = (float*)(ws + off); off += (size_t)B_ * E_ * K_ * sizeof(float);  // 128 KB
  off = (off + 255) & ~(size_t)255;
  unsigned short* WgT = (unsigned short*)(ws + off); off += (size_t)E_ * D_ * I_ * 2; // 32 MB
  unsigned short* WuT = (unsigned short*)(ws + off); off += (size_t)E_ * D_ * I_ * 2; // 32 MB
  unsigned short* WdT = (unsigned short*)(ws + off); off += (size_t)E_ * D_ * I_ * 2; // 32 MB
  unsigned short* Xsel = (unsigned short*)(ws + off); off += (size_t)B_ * E_ * K_ * D_ * 2; // 64 MB
  off = (off + 255) & ~(size_t)255;
  unsigned short* H = (unsigned short*)(ws + off);
  size_t rem = (ws_size > off) ? (ws_size - off) : 0;

  int Ic = 128;  // I-chunk for H buffer, sized to workspace
  for (int c = I_; c >= 128; c >>= 1) {
    if ((size_t)B_ * E_ * K_ * (size_t)c * 2 <= rem) { Ic = c; break; }
  }

  hipMemsetAsync(d_out, 0, (size_t)out_size * sizeof(float), stream);
  router_kernel<<<B_ * S_ / 4, 256, 0, stream>>>(x, gw, affD);
  topk_kernel<<<B_ * E_, 1024, 0, stream>>>(affD, idxArr, gateArr);
  // weight pre-transpose+convert: Wg,Wu [D][I] -> [I][D]; Wd [I][D] -> [D][I]
  transpose_cvt_kernel<<<dim3((D_ / 64) * (I_ / 64), E_), 256, 0, stream>>>(Wg, WgT, D_, I_);
  transpose_cvt_kernel<<<dim3((D_ / 64) * (I_ / 64), E_), 256, 0, stream>>>(Wu, WuT, D_, I_);
  transpose_cvt_kernel<<<dim3((I_ / 64) * (D_ / 64), E_), 256, 0, stream>>>(Wd, WdT, I_, D_);
  gather_cvt_kernel<<<B_ * E_ * K_ / 4, 256, 0, stream>>>(x, idxArr, Xsel);
  for (int i0 = 0; i0 < I_; i0 += Ic) {
    mlp1_kernel<<<B_ * E_ * 8 * (Ic / 128), 256, 0, stream>>>(Xsel, WgT, WuT, H, Ic, i0);
    mlp2_kernel<<<B_ * E_ * 8 * 8, 256, 0, stream>>>(H, WdT, idxArr, gateArr, out, Ic, i0);
  }
}